// Round 9
// baseline (231.525 us; speedup 1.0000x reference)
//
#include <hip/hip_runtime.h>

// Problem constants (fixed by setup_inputs)
constexpr int NI = 64;    // images
constexpr int NC = 64;    // captions
constexpr int RR = 36;    // regions
constexpr int WW = 32;    // max words
constexpr int DI = 2048;  // img_dim
constexpr int DD = 1024;  // d
constexpr int MROWS = NI * RR;  // 2304
constexpr int NCOLS = NC * WW;  // 2048

#define EPSV 1e-8f
#define LAM_SM 9.0f
#define LAM_LSE 6.0f
#define LEAKY_S 0.1f

typedef __bf16 bf16x8 __attribute__((ext_vector_type(8)));
typedef float f32x4 __attribute__((ext_vector_type(4)));
typedef unsigned short ushort8v __attribute__((ext_vector_type(8)));
typedef unsigned short ushort4v __attribute__((ext_vector_type(4)));

__device__ __forceinline__ unsigned short f2bf(float f) {
    unsigned int u = __builtin_bit_cast(unsigned int, f);
    unsigned int r = (u + 0x7fffu + ((u >> 16) & 1u)) >> 16;
    return (unsigned short)r;
}

#define GLOAD16(gp, lp)                                                              \
    __builtin_amdgcn_global_load_lds(                                                \
        (const __attribute__((address_space(1))) unsigned int*)(gp),                 \
        (__attribute__((address_space(3))) unsigned int*)(lp), 16, 0, 0)

// ---------------- fused prep: images->bf16 | W_fc transpose->bf16 | capnorm ----------------
__global__ __launch_bounds__(256) void prep(const float* __restrict__ images,
                                            const float* __restrict__ W,
                                            const float* __restrict__ cap,
                                            unsigned short* __restrict__ images_bf,
                                            unsigned short* __restrict__ Wt,
                                            unsigned short* __restrict__ capn_bf,
                                            float* __restrict__ w1)
{
    const int b = blockIdx.x, tid = threadIdx.x;
    if (b < 2304) {
        int i = b * 256 + tid;
        const float4* X4 = reinterpret_cast<const float4*>(images);
        float4 a = X4[i * 2], c = X4[i * 2 + 1];
        ushort8v o;
        o[0] = f2bf(a.x); o[1] = f2bf(a.y); o[2] = f2bf(a.z); o[3] = f2bf(a.w);
        o[4] = f2bf(c.x); o[5] = f2bf(c.y); o[6] = f2bf(c.z); o[7] = f2bf(c.w);
        *reinterpret_cast<ushort8v*>(&images_bf[i * 8]) = o;
    } else if (b < 4352) {
        __shared__ float t[32][33];
        int bi = b - 2304;
        int bk = (bi >> 5) * 32;
        int bn = (bi & 31) * 32;
        int x = tid & 31, y0 = tid >> 5;
        for (int yy = y0; yy < 32; yy += 8)
            t[yy][x] = W[(bk + yy) * DD + bn + x];
        __syncthreads();
        for (int yy = y0; yy < 32; yy += 8)
            Wt[(bn + yy) * DI + bk + x] = f2bf(t[x][yy]);
    } else {
        int row = b - 4352;
        float4 v = *reinterpret_cast<const float4*>(&cap[row * 1024 + tid * 4]);
        float s = v.x * v.x + v.y * v.y + v.z * v.z + v.w * v.w;
        #pragma unroll
        for (int off = 32; off; off >>= 1) s += __shfl_down(s, off);
        __shared__ float ps[4];
        if ((tid & 63) == 0) ps[tid >> 6] = s;
        __syncthreads();
        float tot = ps[0] + ps[1] + ps[2] + ps[3];
        float n = sqrtf(tot);
        float inv = 1.0f / (n + EPSV);
        v.x *= inv; v.y *= inv; v.z *= inv; v.w *= inv;
        ushort4v o;
        o[0] = f2bf(v.x); o[1] = f2bf(v.y); o[2] = f2bf(v.z); o[3] = f2bf(v.w);
        *reinterpret_cast<ushort4v*>(&capn_bf[row * 1024 + tid * 4]) = o;
        if (tid == 0) w1[row] = n * inv;
    }
}

// ---------------- projection GEMM: 64x128 tile, BK=64, XOR-swizzled LDS, split-K (R8-proven) ----------------
template <int M, int N, int K, int KS>
__global__ __launch_bounds__(256) void gemm_proj64(const unsigned short* __restrict__ A,
                                                   const unsigned short* __restrict__ Bt,
                                                   float* __restrict__ C)
{
    __shared__ __align__(16) unsigned short As[64 * 64];   // 8 KB
    __shared__ __align__(16) unsigned short Bs[128 * 64];  // 16 KB
    const int tid = threadIdx.x;
    const int w = tid >> 6, lane = tid & 63;
    const int bm = blockIdx.x * 64, bn = blockIdx.y * 128;
    const int klo = blockIdx.z * (K / KS);
    const int wr = w >> 1, wc = w & 1;
    const int hi = lane >> 4, fr = lane & 15;

    f32x4 acc[2][4] = {};

    const unsigned short* gA[2];
    const unsigned short* gB[4];
    unsigned short* lA[2];
    unsigned short* lB[4];
    #pragma unroll
    for (int n = 0; n < 2; ++n) {
        int s = tid + n * 256;
        int row = s >> 3, j = (s & 7) ^ (row & 7);
        gA[n] = &A[(size_t)(bm + row) * K + klo + j * 8];
        lA[n] = &As[s * 8];
    }
    #pragma unroll
    for (int n = 0; n < 4; ++n) {
        int s = tid + n * 256;
        int row = s >> 3, j = (s & 7) ^ (row & 7);
        gB[n] = &Bt[(size_t)(bn + row) * K + klo + j * 8];
        lB[n] = &Bs[s * 8];
    }

    for (int k0 = 0; k0 < K / KS; k0 += 64) {
        __syncthreads();
        #pragma unroll
        for (int n = 0; n < 2; ++n) GLOAD16(gA[n] + k0, lA[n]);
        #pragma unroll
        for (int n = 0; n < 4; ++n) GLOAD16(gB[n] + k0, lB[n]);
        __syncthreads();
        #pragma unroll
        for (int ks = 0; ks < 2; ++ks) {
            bf16x8 af[2], bfv[4];
            #pragma unroll
            for (int mi = 0; mi < 2; ++mi) {
                int row = wr * 32 + mi * 16 + fr;
                af[mi] = *reinterpret_cast<const bf16x8*>(
                    &As[row * 64 + ((((ks << 2) + hi) ^ (row & 7)) << 3)]);
            }
            #pragma unroll
            for (int ni = 0; ni < 4; ++ni) {
                int row = wc * 64 + ni * 16 + fr;
                bfv[ni] = *reinterpret_cast<const bf16x8*>(
                    &Bs[row * 64 + ((((ks << 2) + hi) ^ (row & 7)) << 3)]);
            }
            #pragma unroll
            for (int mi = 0; mi < 2; ++mi)
                #pragma unroll
                for (int ni = 0; ni < 4; ++ni)
                    acc[mi][ni] = __builtin_amdgcn_mfma_f32_16x16x32_bf16(af[mi], bfv[ni], acc[mi][ni], 0, 0, 0);
        }
    }

    float* Cz = C + (size_t)blockIdx.z * M * N;
    const int cr0 = hi * 4, cc = fr;
    #pragma unroll
    for (int mi = 0; mi < 2; ++mi) {
        int row0 = bm + wr * 32 + mi * 16 + cr0;
        #pragma unroll
        for (int ni = 0; ni < 4; ++ni) {
            int col = bn + wc * 64 + ni * 16 + cc;
            #pragma unroll
            for (int r = 0; r < 4; ++r)
                Cz[(size_t)(row0 + r) * N + col] = acc[mi][ni][r];
        }
    }
}

// ---------------- rownorm: v = part0 + part1 + bias; l2norm; bf16 out only ----------------
// (f32 writeback dropped — gram is now fused into sim_fused, so nothing reads f32 emb)
__global__ __launch_bounds__(256) void rownorm_add(const float* __restrict__ P0,
                                                   const float* __restrict__ P1,
                                                   const float* __restrict__ bias,
                                                   unsigned short* __restrict__ Xbf)
{
    const int row = blockIdx.x;
    const int t4 = threadIdx.x * 4;
    float4 a = *reinterpret_cast<const float4*>(&P0[row * 1024 + t4]);
    float4 b = *reinterpret_cast<const float4*>(&P1[row * 1024 + t4]);
    float4 c = *reinterpret_cast<const float4*>(&bias[t4]);
    float4 v = {a.x + b.x + c.x, a.y + b.y + c.y, a.z + b.z + c.z, a.w + b.w + c.w};
    float s = v.x * v.x + v.y * v.y + v.z * v.z + v.w * v.w;
    #pragma unroll
    for (int off = 32; off; off >>= 1) s += __shfl_down(s, off);
    __shared__ float ps[4];
    if ((threadIdx.x & 63) == 0) ps[threadIdx.x >> 6] = s;
    __syncthreads();
    float tot = ps[0] + ps[1] + ps[2] + ps[3];
    float inv = 1.0f / (sqrtf(tot) + EPSV);
    v.x *= inv; v.y *= inv; v.z *= inv; v.w *= inv;
    ushort4v o;
    o[0] = f2bf(v.x); o[1] = f2bf(v.y); o[2] = f2bf(v.z); o[3] = f2bf(v.w);
    *reinterpret_cast<ushort4v*>(&Xbf[row * 1024 + t4]) = o;
}

// ---------------- fused S-GEMM + Gram + epilogue (R5/R8 4-wave structure) ----------------
// block = (cg, i): image i x captions [cg*4, cg*4+4). Wave w = caption cg*4+w.
// NEW: G = E E^T computed in the same K-loop. af[mi] fragments double as both
// MFMA operands (identical LDS read pattern), so wave w<3 adds gacc[j] =
// mfma(af[w], af[j]) — 3 extra MFMAs/k-step. Gb fragment writes land before
// the existing post-P2 __syncthreads(), which orders them for P3. Gb cols
// 48..63 zeroed at start (stale LDS as bf16 can be NaN; 0*NaN would poison P3).
__global__ __launch_bounds__(256) void sim_fused(const unsigned short* __restrict__ img_bf,
                                                 const unsigned short* __restrict__ capn_bf,
                                                 const float* __restrict__ w1v,
                                                 const int* __restrict__ cap_lens,
                                                 float* __restrict__ out)
{
    __shared__ __align__(16) unsigned short As[48 * 32];    // 3 KB
    __shared__ __align__(16) unsigned short Bs[128 * 32];   // 8 KB
    __shared__ __align__(16) unsigned short Gb[48 * 64];    // 6 KB
    __shared__ __align__(16) unsigned short Eb[4][32 * 64]; // 16 KB
    const int tid = threadIdx.x;
    const int w = tid >> 6, lane = tid & 63;
    const int i = blockIdx.y, cg = blockIdx.x;
    const int c = cg * 4 + w;
    const int hi = lane >> 4, lo = lane & 15;

    // zero Gb cols 48..63 (all 48 rows) and Eb cols 48..63
    {
        unsigned int* gdst = (unsigned int*)Gb;
        for (int e = tid; e < 48 * 8; e += 256)
            gdst[(e >> 3) * 32 + 24 + (e & 7)] = 0;
        unsigned int* ed = (unsigned int*)Eb;
        for (int e2 = tid; e2 < 4 * 32 * 8; e2 += 256) {
            int slab = e2 >> 8, rem = e2 & 255;
            ed[slab * 1024 + (rem >> 3) * 32 + 24 + (rem & 7)] = 0;
        }
    }

    // ---- S GEMM (48x128, K=1024) + G GEMM (48x48, same K) ----
    f32x4 acc[3][2] = {};
    f32x4 gacc[3] = {};   // wave w<3: G fragments (rows w*16.., cols j*16..)
    const unsigned short* gA0 = &img_bf[(size_t)(i * RR + (tid >> 2)) * DD + (tid & 3) * 8];
    const unsigned short* gB0 = &capn_bf[(size_t)(cg * 128 + (tid >> 2)) * DD + (tid & 3) * 8];
    unsigned short* lA0 = &As[w * 512];   // waves 0..2 only
    unsigned short* lB0 = &Bs[w * 512];
    const int kgrp = hi * 8;

    for (int k0 = 0; k0 < DD; k0 += 32) {
        __syncthreads();
        if (w < 3) GLOAD16(gA0 + k0, lA0);
        GLOAD16(gB0 + k0, lB0);
        GLOAD16(gB0 + 64 * DD + k0, lB0 + 2048);
        __syncthreads();
        bf16x8 b0 = *reinterpret_cast<const bf16x8*>(&Bs[(w * 32 + lo) * 32 + kgrp]);
        bf16x8 b1 = *reinterpret_cast<const bf16x8*>(&Bs[(w * 32 + 16 + lo) * 32 + kgrp]);
        bf16x8 af[3];
        #pragma unroll
        for (int mi = 0; mi < 3; ++mi)
            af[mi] = *reinterpret_cast<const bf16x8*>(&As[(mi * 16 + lo) * 32 + kgrp]);
        #pragma unroll
        for (int mi = 0; mi < 3; ++mi) {
            acc[mi][0] = __builtin_amdgcn_mfma_f32_16x16x32_bf16(af[mi], b0, acc[mi][0], 0, 0, 0);
            acc[mi][1] = __builtin_amdgcn_mfma_f32_16x16x32_bf16(af[mi], b1, acc[mi][1], 0, 0, 0);
        }
        if (w < 3) {
            #pragma unroll
            for (int j = 0; j < 3; ++j)
                gacc[j] = __builtin_amdgcn_mfma_f32_16x16x32_bf16(af[w], af[j], gacc[j], 0, 0, 0);
        }
    }
    // acc[mi][ni][reg] = S[r = mi*16 + hi*4 + reg][wcol = ni*16 + lo]
    // gacc[j][reg]     = G[r = w*16 + hi*4 + reg][r' = j*16 + lo]

    // write G fragments to Gb (cols 0..47; cols 48..63 pre-zeroed)
    if (w < 3) {
        #pragma unroll
        for (int j = 0; j < 3; ++j)
            #pragma unroll
            for (int reg = 0; reg < 4; ++reg)
                Gb[(w * 16 + hi * 4 + reg) * 64 + j * 16 + lo] = f2bf(gacc[j][reg]);
    }

    const int len = cap_lens[c];

    // ---- P1: leaky+mask, l2norm over words (per r) ----
    float a1[3][2][4];
    #pragma unroll
    for (int mi = 0; mi < 3; ++mi)
        #pragma unroll
        for (int reg = 0; reg < 4; ++reg) {
            int r = mi * 16 + hi * 4 + reg;
            float v0 = acc[mi][0][reg]; v0 = v0 > 0.f ? v0 : LEAKY_S * v0; v0 = (lo < len) ? v0 : 0.f;
            float v1 = acc[mi][1][reg]; v1 = v1 > 0.f ? v1 : LEAKY_S * v1; v1 = (16 + lo < len) ? v1 : 0.f;
            float ss = v0 * v0 + v1 * v1;
            ss += __shfl_xor(ss, 1); ss += __shfl_xor(ss, 2);
            ss += __shfl_xor(ss, 4); ss += __shfl_xor(ss, 8);
            float inv = 1.0f / (sqrtf(ss) + EPSV);
            bool valid = r < RR;
            a1[mi][0][reg] = valid ? v0 * inv : -1e30f;
            a1[mi][1][reg] = valid ? v1 * inv : -1e30f;
        }

    // ---- P2: col max over r; e = exp(9(a1-m)); w12 partial; Eb write ----
    float m0 = -1e30f, m1 = -1e30f;
    #pragma unroll
    for (int mi = 0; mi < 3; ++mi)
        #pragma unroll
        for (int reg = 0; reg < 4; ++reg) {
            m0 = fmaxf(m0, a1[mi][0][reg]);
            m1 = fmaxf(m1, a1[mi][1][reg]);
        }
    m0 = fmaxf(m0, __shfl_xor(m0, 16)); m0 = fmaxf(m0, __shfl_xor(m0, 32));
    m1 = fmaxf(m1, __shfl_xor(m1, 16)); m1 = fmaxf(m1, __shfl_xor(m1, 32));

    float e_[3][2][4];
    float w12p0 = 0.f, w12p1 = 0.f;
    #pragma unroll
    for (int mi = 0; mi < 3; ++mi)
        #pragma unroll
        for (int reg = 0; reg < 4; ++reg) {
            int r = mi * 16 + hi * 4 + reg;
            bool valid = r < RR;
            float e0 = valid ? __expf(LAM_SM * (a1[mi][0][reg] - m0)) : 0.f;
            float e1 = valid ? __expf(LAM_SM * (a1[mi][1][reg] - m1)) : 0.f;
            e_[mi][0][reg] = e0; e_[mi][1][reg] = e1;
            w12p0 += e0 * acc[mi][0][reg];
            w12p1 += e1 * acc[mi][1][reg];
            Eb[w][(lo) * 64 + r] = f2bf(e0);
            Eb[w][(16 + lo) * 64 + r] = f2bf(e1);
        }
    w12p0 += __shfl_xor(w12p0, 16); w12p0 += __shfl_xor(w12p0, 32);
    w12p1 += __shfl_xor(w12p1, 16); w12p1 += __shfl_xor(w12p1, 32);
    __syncthreads();   // orders Gb + Eb ds_writes before P3 ds_reads

    // ---- P3: T = G (48xK) x E^T (K x 32 words) via MFMA, K = 64 (padded) ----
    f32x4 T[3][2] = {};
    #pragma unroll
    for (int kk = 0; kk < 2; ++kk) {
        int kg2 = kk * 32 + hi * 8;
        bf16x8 eb0 = *reinterpret_cast<const bf16x8*>(&Eb[w][(lo) * 64 + kg2]);
        bf16x8 eb1 = *reinterpret_cast<const bf16x8*>(&Eb[w][(16 + lo) * 64 + kg2]);
        #pragma unroll
        for (int mi = 0; mi < 3; ++mi) {
            bf16x8 gf = *reinterpret_cast<const bf16x8*>(&Gb[(mi * 16 + lo) * 64 + kg2]);
            T[mi][0] = __builtin_amdgcn_mfma_f32_16x16x32_bf16(gf, eb0, T[mi][0], 0, 0, 0);
            T[mi][1] = __builtin_amdgcn_mfma_f32_16x16x32_bf16(gf, eb1, T[mi][1], 0, 0, 0);
        }
    }
    // w2sq = sum_r e * T   (garbage rows have e = 0; garbage G rows/cols neutralized)
    float w20 = 0.f, w21 = 0.f;
    #pragma unroll
    for (int mi = 0; mi < 3; ++mi)
        #pragma unroll
        for (int reg = 0; reg < 4; ++reg) {
            w20 += e_[mi][0][reg] * T[mi][0][reg];
            w21 += e_[mi][1][reg] * T[mi][1][reg];
        }
    w20 += __shfl_xor(w20, 16); w20 += __shfl_xor(w20, 32);
    w21 += __shfl_xor(w21, 16); w21 += __shfl_xor(w21, 32);

    // ---- P4+P5: row_sim, masked exp, LSE over words ----
    float ew = 0.f;
    if (lo < len) {
        float rs = w12p0 / fmaxf(w1v[c * WW + lo] * sqrtf(fmaxf(w20, 0.f)), 1e-30f);
        ew += __expf(LAM_LSE * rs);
    }
    if (16 + lo < len) {
        float rs = w12p1 / fmaxf(w1v[c * WW + 16 + lo] * sqrtf(fmaxf(w21, 0.f)), 1e-30f);
        ew += __expf(LAM_LSE * rs);
    }
    ew += __shfl_xor(ew, 1); ew += __shfl_xor(ew, 2);
    ew += __shfl_xor(ew, 4); ew += __shfl_xor(ew, 8);
    if (lane == 0) out[i * NC + c] = logf(ew) / LAM_LSE;
}

extern "C" void kernel_launch(void* const* d_in, const int* in_sizes, int n_in,
                              void* d_out, int out_size, void* d_ws, size_t ws_size,
                              hipStream_t stream)
{
    const float* images   = (const float*)d_in[0];
    const float* cap_emb  = (const float*)d_in[1];
    const float* W_fc     = (const float*)d_in[2];
    const float* b_fc     = (const float*)d_in[3];
    const int*   cap_lens = (const int*)d_in[4];
    float* out = (float*)d_out;

    char* ws = (char*)d_ws;
    float*          part0     = (float*)(ws);                       //  9,437,184
    float*          part1     = (float*)(ws + 9437184);             //  9,437,184
    unsigned short* images_bf = (unsigned short*)(ws + 18874368);   //  9,437,184
    unsigned short* Wt        = (unsigned short*)(ws + 28311552);   //  4,194,304
    unsigned short* img_bf    = (unsigned short*)(ws + 32505856);   //  4,718,592
    unsigned short* capn_bf   = (unsigned short*)(ws + 37224448);   //  4,194,304 (absorbs 24KB garbage-row overrun reads)
    float*          w1        = (float*)(ws + 41713664);            //      8,192

    // 1. fused prep: images->bf16 | Wt | capnorm(+w1)
    prep<<<6400, 256, 0, stream>>>(images, W_fc, cap_emb, images_bf, Wt, capn_bf, w1);
    // 2. split-K=2 projection GEMM, 64x128 tiles, BK=64 swizzled
    gemm_proj64<MROWS, DD, DI, 2><<<dim3(MROWS / 64, DD / 128, 2), 256, 0, stream>>>(images_bf, Wt, part0);
    // 3. sum halves + bias, l2norm -> bf16 only
    rownorm_add<<<MROWS, 256, 0, stream>>>(part0, part1, b_fc, img_bf);
    // 4. fused S-GEMM + Gram + epilogue
    sim_fused<<<dim3(16, NI), 256, 0, stream>>>(img_bf, capn_bf, w1, cap_lens, out);
}

// Round 10
// 150.640 us; speedup vs baseline: 1.5369x; 1.5369x over previous
//
#include <hip/hip_runtime.h>

// Problem constants (fixed by setup_inputs)
constexpr int NI = 64;    // images
constexpr int NC = 64;    // captions
constexpr int RR = 36;    // regions
constexpr int WW = 32;    // max words
constexpr int DI = 2048;  // img_dim
constexpr int DD = 1024;  // d
constexpr int MROWS = NI * RR;  // 2304
constexpr int NCOLS = NC * WW;  // 2048

#define EPSV 1e-8f
#define LAM_SM 9.0f
#define LAM_LSE 6.0f
#define LEAKY_S 0.1f

typedef __bf16 bf16x8 __attribute__((ext_vector_type(8)));
typedef float f32x4 __attribute__((ext_vector_type(4)));
typedef unsigned short ushort8v __attribute__((ext_vector_type(8)));
typedef unsigned short ushort4v __attribute__((ext_vector_type(4)));

__device__ __forceinline__ unsigned short f2bf(float f) {
    unsigned int u = __builtin_bit_cast(unsigned int, f);
    unsigned int r = (u + 0x7fffu + ((u >> 16) & 1u)) >> 16;
    return (unsigned short)r;
}

#define GLOAD16(gp, lp)                                                              \
    __builtin_amdgcn_global_load_lds(                                                \
        (const __attribute__((address_space(1))) unsigned int*)(gp),                 \
        (__attribute__((address_space(3))) unsigned int*)(lp), 16, 0, 0)

// ---------------- fused prep: images->bf16 | W_fc transpose->bf16 | capnorm ----------------
__global__ __launch_bounds__(256) void prep(const float* __restrict__ images,
                                            const float* __restrict__ W,
                                            const float* __restrict__ cap,
                                            unsigned short* __restrict__ images_bf,
                                            unsigned short* __restrict__ Wt,
                                            unsigned short* __restrict__ capn_bf,
                                            float* __restrict__ w1)
{
    const int b = blockIdx.x, tid = threadIdx.x;
    if (b < 2304) {
        int i = b * 256 + tid;
        const float4* X4 = reinterpret_cast<const float4*>(images);
        float4 a = X4[i * 2], c = X4[i * 2 + 1];
        ushort8v o;
        o[0] = f2bf(a.x); o[1] = f2bf(a.y); o[2] = f2bf(a.z); o[3] = f2bf(a.w);
        o[4] = f2bf(c.x); o[5] = f2bf(c.y); o[6] = f2bf(c.z); o[7] = f2bf(c.w);
        *reinterpret_cast<ushort8v*>(&images_bf[i * 8]) = o;
    } else if (b < 4352) {
        __shared__ float t[32][33];
        int bi = b - 2304;
        int bk = (bi >> 5) * 32;
        int bn = (bi & 31) * 32;
        int x = tid & 31, y0 = tid >> 5;
        for (int yy = y0; yy < 32; yy += 8)
            t[yy][x] = W[(bk + yy) * DD + bn + x];
        __syncthreads();
        for (int yy = y0; yy < 32; yy += 8)
            Wt[(bn + yy) * DI + bk + x] = f2bf(t[x][yy]);
    } else {
        int row = b - 4352;
        float4 v = *reinterpret_cast<const float4*>(&cap[row * 1024 + tid * 4]);
        float s = v.x * v.x + v.y * v.y + v.z * v.z + v.w * v.w;
        #pragma unroll
        for (int off = 32; off; off >>= 1) s += __shfl_down(s, off);
        __shared__ float ps[4];
        if ((tid & 63) == 0) ps[tid >> 6] = s;
        __syncthreads();
        float tot = ps[0] + ps[1] + ps[2] + ps[3];
        float n = sqrtf(tot);
        float inv = 1.0f / (n + EPSV);
        v.x *= inv; v.y *= inv; v.z *= inv; v.w *= inv;
        ushort4v o;
        o[0] = f2bf(v.x); o[1] = f2bf(v.y); o[2] = f2bf(v.z); o[3] = f2bf(v.w);
        *reinterpret_cast<ushort4v*>(&capn_bf[row * 1024 + tid * 4]) = o;
        if (tid == 0) w1[row] = n * inv;
    }
}

// ---------------- projection GEMM: 64x128 tile, BK=64, XOR-swizzled LDS, split-K (R8-proven) ----------------
template <int M, int N, int K, int KS>
__global__ __launch_bounds__(256) void gemm_proj64(const unsigned short* __restrict__ A,
                                                   const unsigned short* __restrict__ Bt,
                                                   float* __restrict__ C)
{
    __shared__ __align__(16) unsigned short As[64 * 64];   // 8 KB
    __shared__ __align__(16) unsigned short Bs[128 * 64];  // 16 KB
    const int tid = threadIdx.x;
    const int w = tid >> 6, lane = tid & 63;
    const int bm = blockIdx.x * 64, bn = blockIdx.y * 128;
    const int klo = blockIdx.z * (K / KS);
    const int wr = w >> 1, wc = w & 1;
    const int hi = lane >> 4, fr = lane & 15;

    f32x4 acc[2][4] = {};

    const unsigned short* gA[2];
    const unsigned short* gB[4];
    unsigned short* lA[2];
    unsigned short* lB[4];
    #pragma unroll
    for (int n = 0; n < 2; ++n) {
        int s = tid + n * 256;
        int row = s >> 3, j = (s & 7) ^ (row & 7);
        gA[n] = &A[(size_t)(bm + row) * K + klo + j * 8];
        lA[n] = &As[s * 8];
    }
    #pragma unroll
    for (int n = 0; n < 4; ++n) {
        int s = tid + n * 256;
        int row = s >> 3, j = (s & 7) ^ (row & 7);
        gB[n] = &Bt[(size_t)(bn + row) * K + klo + j * 8];
        lB[n] = &Bs[s * 8];
    }

    for (int k0 = 0; k0 < K / KS; k0 += 64) {
        __syncthreads();
        #pragma unroll
        for (int n = 0; n < 2; ++n) GLOAD16(gA[n] + k0, lA[n]);
        #pragma unroll
        for (int n = 0; n < 4; ++n) GLOAD16(gB[n] + k0, lB[n]);
        __syncthreads();
        #pragma unroll
        for (int ks = 0; ks < 2; ++ks) {
            bf16x8 af[2], bfv[4];
            #pragma unroll
            for (int mi = 0; mi < 2; ++mi) {
                int row = wr * 32 + mi * 16 + fr;
                af[mi] = *reinterpret_cast<const bf16x8*>(
                    &As[row * 64 + ((((ks << 2) + hi) ^ (row & 7)) << 3)]);
            }
            #pragma unroll
            for (int ni = 0; ni < 4; ++ni) {
                int row = wc * 64 + ni * 16 + fr;
                bfv[ni] = *reinterpret_cast<const bf16x8*>(
                    &Bs[row * 64 + ((((ks << 2) + hi) ^ (row & 7)) << 3)]);
            }
            #pragma unroll
            for (int mi = 0; mi < 2; ++mi)
                #pragma unroll
                for (int ni = 0; ni < 4; ++ni)
                    acc[mi][ni] = __builtin_amdgcn_mfma_f32_16x16x32_bf16(af[mi], bfv[ni], acc[mi][ni], 0, 0, 0);
        }
    }

    float* Cz = C + (size_t)blockIdx.z * M * N;
    const int cr0 = hi * 4, cc = fr;
    #pragma unroll
    for (int mi = 0; mi < 2; ++mi) {
        int row0 = bm + wr * 32 + mi * 16 + cr0;
        #pragma unroll
        for (int ni = 0; ni < 4; ++ni) {
            int col = bn + wc * 64 + ni * 16 + cc;
            #pragma unroll
            for (int r = 0; r < 4; ++r)
                Cz[(size_t)(row0 + r) * N + col] = acc[mi][ni][r];
        }
    }
}

// ---------------- rownorm: v = part0 + part1 + bias; l2norm; bf16 out only ----------------
__global__ __launch_bounds__(256) void rownorm_add(const float* __restrict__ P0,
                                                   const float* __restrict__ P1,
                                                   const float* __restrict__ bias,
                                                   unsigned short* __restrict__ Xbf)
{
    const int row = blockIdx.x;
    const int t4 = threadIdx.x * 4;
    float4 a = *reinterpret_cast<const float4*>(&P0[row * 1024 + t4]);
    float4 b = *reinterpret_cast<const float4*>(&P1[row * 1024 + t4]);
    float4 c = *reinterpret_cast<const float4*>(&bias[t4]);
    float4 v = {a.x + b.x + c.x, a.y + b.y + c.y, a.z + b.z + c.z, a.w + b.w + c.w};
    float s = v.x * v.x + v.y * v.y + v.z * v.z + v.w * v.w;
    #pragma unroll
    for (int off = 32; off; off >>= 1) s += __shfl_down(s, off);
    __shared__ float ps[4];
    if ((threadIdx.x & 63) == 0) ps[threadIdx.x >> 6] = s;
    __syncthreads();
    float tot = ps[0] + ps[1] + ps[2] + ps[3];
    float inv = 1.0f / (sqrtf(tot) + EPSV);
    v.x *= inv; v.y *= inv; v.z *= inv; v.w *= inv;
    ushort4v o;
    o[0] = f2bf(v.x); o[1] = f2bf(v.y); o[2] = f2bf(v.z); o[3] = f2bf(v.w);
    *reinterpret_cast<ushort4v*>(&Xbf[row * 1024 + t4]) = o;
}

// ---------------- fused S-GEMM + Gram + epilogue (rule-#20-fixed Gram MFMAs) ----------------
// block = (cg, i): image i x captions [cg*4, cg*4+4). Wave w = caption cg*4+w.
// Gram fragments computed in the same K-loop as the S-GEMM. All MFMA operand
// registers are STATIC (named af0/af1/af2, gacc0/1/2) selected by a
// wave-uniform 3-way branch — no runtime-indexed register arrays (rule #20;
// R9's af[w] went to scratch, 5x slowdown).
__global__ __launch_bounds__(256) void sim_fused(const unsigned short* __restrict__ img_bf,
                                                 const unsigned short* __restrict__ capn_bf,
                                                 const float* __restrict__ w1v,
                                                 const int* __restrict__ cap_lens,
                                                 float* __restrict__ out)
{
    __shared__ __align__(16) unsigned short As[48 * 32];    // 3 KB
    __shared__ __align__(16) unsigned short Bs[128 * 32];   // 8 KB
    __shared__ __align__(16) unsigned short Gb[48 * 64];    // 6 KB
    __shared__ __align__(16) unsigned short Eb[4][32 * 64]; // 16 KB
    const int tid = threadIdx.x;
    const int w = tid >> 6, lane = tid & 63;
    const int i = blockIdx.y, cg = blockIdx.x;
    const int c = cg * 4 + w;
    const int hi = lane >> 4, lo = lane & 15;

    // zero Gb cols 48..63 (all 48 rows) and Eb cols 48..63
    {
        unsigned int* gdst = (unsigned int*)Gb;
        for (int e = tid; e < 48 * 8; e += 256)
            gdst[(e >> 3) * 32 + 24 + (e & 7)] = 0;
        unsigned int* ed = (unsigned int*)Eb;
        for (int e2 = tid; e2 < 4 * 32 * 8; e2 += 256) {
            int slab = e2 >> 8, rem = e2 & 255;
            ed[slab * 1024 + (rem >> 3) * 32 + 24 + (rem & 7)] = 0;
        }
    }

    // ---- S GEMM (48x128, K=1024) + G GEMM (48x48, same K) ----
    f32x4 acc[3][2] = {};
    f32x4 gacc0 = {0.f, 0.f, 0.f, 0.f}, gacc1 = {0.f, 0.f, 0.f, 0.f}, gacc2 = {0.f, 0.f, 0.f, 0.f};
    const unsigned short* gA0 = &img_bf[(size_t)(i * RR + (tid >> 2)) * DD + (tid & 3) * 8];
    const unsigned short* gB0 = &capn_bf[(size_t)(cg * 128 + (tid >> 2)) * DD + (tid & 3) * 8];
    unsigned short* lA0 = &As[w * 512];   // waves 0..2 only
    unsigned short* lB0 = &Bs[w * 512];
    const int kgrp = hi * 8;

    for (int k0 = 0; k0 < DD; k0 += 32) {
        __syncthreads();
        if (w < 3) GLOAD16(gA0 + k0, lA0);
        GLOAD16(gB0 + k0, lB0);
        GLOAD16(gB0 + 64 * DD + k0, lB0 + 2048);
        __syncthreads();
        bf16x8 b0 = *reinterpret_cast<const bf16x8*>(&Bs[(w * 32 + lo) * 32 + kgrp]);
        bf16x8 b1 = *reinterpret_cast<const bf16x8*>(&Bs[(w * 32 + 16 + lo) * 32 + kgrp]);
        bf16x8 af0 = *reinterpret_cast<const bf16x8*>(&As[(0 * 16 + lo) * 32 + kgrp]);
        bf16x8 af1 = *reinterpret_cast<const bf16x8*>(&As[(1 * 16 + lo) * 32 + kgrp]);
        bf16x8 af2 = *reinterpret_cast<const bf16x8*>(&As[(2 * 16 + lo) * 32 + kgrp]);
        acc[0][0] = __builtin_amdgcn_mfma_f32_16x16x32_bf16(af0, b0, acc[0][0], 0, 0, 0);
        acc[0][1] = __builtin_amdgcn_mfma_f32_16x16x32_bf16(af0, b1, acc[0][1], 0, 0, 0);
        acc[1][0] = __builtin_amdgcn_mfma_f32_16x16x32_bf16(af1, b0, acc[1][0], 0, 0, 0);
        acc[1][1] = __builtin_amdgcn_mfma_f32_16x16x32_bf16(af1, b1, acc[1][1], 0, 0, 0);
        acc[2][0] = __builtin_amdgcn_mfma_f32_16x16x32_bf16(af2, b0, acc[2][0], 0, 0, 0);
        acc[2][1] = __builtin_amdgcn_mfma_f32_16x16x32_bf16(af2, b1, acc[2][1], 0, 0, 0);
        // Gram: wave-uniform branch, all operands static registers
        if (w == 0) {
            gacc0 = __builtin_amdgcn_mfma_f32_16x16x32_bf16(af0, af0, gacc0, 0, 0, 0);
            gacc1 = __builtin_amdgcn_mfma_f32_16x16x32_bf16(af0, af1, gacc1, 0, 0, 0);
            gacc2 = __builtin_amdgcn_mfma_f32_16x16x32_bf16(af0, af2, gacc2, 0, 0, 0);
        } else if (w == 1) {
            gacc0 = __builtin_amdgcn_mfma_f32_16x16x32_bf16(af1, af0, gacc0, 0, 0, 0);
            gacc1 = __builtin_amdgcn_mfma_f32_16x16x32_bf16(af1, af1, gacc1, 0, 0, 0);
            gacc2 = __builtin_amdgcn_mfma_f32_16x16x32_bf16(af1, af2, gacc2, 0, 0, 0);
        } else if (w == 2) {
            gacc0 = __builtin_amdgcn_mfma_f32_16x16x32_bf16(af2, af0, gacc0, 0, 0, 0);
            gacc1 = __builtin_amdgcn_mfma_f32_16x16x32_bf16(af2, af1, gacc1, 0, 0, 0);
            gacc2 = __builtin_amdgcn_mfma_f32_16x16x32_bf16(af2, af2, gacc2, 0, 0, 0);
        }
    }
    // acc[mi][ni][reg] = S[r = mi*16 + hi*4 + reg][wcol = ni*16 + lo]
    // gaccJ[reg]       = G[r = w*16 + hi*4 + reg][r' = J*16 + lo]

    // write G fragments to Gb (cols 0..47; cols 48..63 pre-zeroed)
    if (w < 3) {
        #pragma unroll
        for (int reg = 0; reg < 4; ++reg) {
            int grow = (w * 16 + hi * 4 + reg) * 64;
            Gb[grow + 0 * 16 + lo] = f2bf(gacc0[reg]);
            Gb[grow + 1 * 16 + lo] = f2bf(gacc1[reg]);
            Gb[grow + 2 * 16 + lo] = f2bf(gacc2[reg]);
        }
    }

    const int len = cap_lens[c];

    // ---- P1: leaky+mask, l2norm over words (per r) ----
    float a1[3][2][4];
    #pragma unroll
    for (int mi = 0; mi < 3; ++mi)
        #pragma unroll
        for (int reg = 0; reg < 4; ++reg) {
            int r = mi * 16 + hi * 4 + reg;
            float v0 = acc[mi][0][reg]; v0 = v0 > 0.f ? v0 : LEAKY_S * v0; v0 = (lo < len) ? v0 : 0.f;
            float v1 = acc[mi][1][reg]; v1 = v1 > 0.f ? v1 : LEAKY_S * v1; v1 = (16 + lo < len) ? v1 : 0.f;
            float ss = v0 * v0 + v1 * v1;
            ss += __shfl_xor(ss, 1); ss += __shfl_xor(ss, 2);
            ss += __shfl_xor(ss, 4); ss += __shfl_xor(ss, 8);
            float inv = 1.0f / (sqrtf(ss) + EPSV);
            bool valid = r < RR;
            a1[mi][0][reg] = valid ? v0 * inv : -1e30f;
            a1[mi][1][reg] = valid ? v1 * inv : -1e30f;
        }

    // ---- P2: col max over r; e = exp(9(a1-m)); w12 partial; Eb write ----
    float m0 = -1e30f, m1 = -1e30f;
    #pragma unroll
    for (int mi = 0; mi < 3; ++mi)
        #pragma unroll
        for (int reg = 0; reg < 4; ++reg) {
            m0 = fmaxf(m0, a1[mi][0][reg]);
            m1 = fmaxf(m1, a1[mi][1][reg]);
        }
    m0 = fmaxf(m0, __shfl_xor(m0, 16)); m0 = fmaxf(m0, __shfl_xor(m0, 32));
    m1 = fmaxf(m1, __shfl_xor(m1, 16)); m1 = fmaxf(m1, __shfl_xor(m1, 32));

    float e_[3][2][4];
    float w12p0 = 0.f, w12p1 = 0.f;
    #pragma unroll
    for (int mi = 0; mi < 3; ++mi)
        #pragma unroll
        for (int reg = 0; reg < 4; ++reg) {
            int r = mi * 16 + hi * 4 + reg;
            bool valid = r < RR;
            float e0 = valid ? __expf(LAM_SM * (a1[mi][0][reg] - m0)) : 0.f;
            float e1 = valid ? __expf(LAM_SM * (a1[mi][1][reg] - m1)) : 0.f;
            e_[mi][0][reg] = e0; e_[mi][1][reg] = e1;
            w12p0 += e0 * acc[mi][0][reg];
            w12p1 += e1 * acc[mi][1][reg];
            Eb[w][(lo) * 64 + r] = f2bf(e0);
            Eb[w][(16 + lo) * 64 + r] = f2bf(e1);
        }
    w12p0 += __shfl_xor(w12p0, 16); w12p0 += __shfl_xor(w12p0, 32);
    w12p1 += __shfl_xor(w12p1, 16); w12p1 += __shfl_xor(w12p1, 32);
    __syncthreads();   // orders Gb + Eb ds_writes before P3 ds_reads

    // ---- P3: T = G (48xK) x E^T (K x 32 words) via MFMA, K = 64 (padded) ----
    f32x4 T[3][2] = {};
    #pragma unroll
    for (int kk = 0; kk < 2; ++kk) {
        int kg2 = kk * 32 + hi * 8;
        bf16x8 eb0 = *reinterpret_cast<const bf16x8*>(&Eb[w][(lo) * 64 + kg2]);
        bf16x8 eb1 = *reinterpret_cast<const bf16x8*>(&Eb[w][(16 + lo) * 64 + kg2]);
        #pragma unroll
        for (int mi = 0; mi < 3; ++mi) {
            bf16x8 gf = *reinterpret_cast<const bf16x8*>(&Gb[(mi * 16 + lo) * 64 + kg2]);
            T[mi][0] = __builtin_amdgcn_mfma_f32_16x16x32_bf16(gf, eb0, T[mi][0], 0, 0, 0);
            T[mi][1] = __builtin_amdgcn_mfma_f32_16x16x32_bf16(gf, eb1, T[mi][1], 0, 0, 0);
        }
    }
    // w2sq = sum_r e * T   (garbage rows have e = 0)
    float w20 = 0.f, w21 = 0.f;
    #pragma unroll
    for (int mi = 0; mi < 3; ++mi)
        #pragma unroll
        for (int reg = 0; reg < 4; ++reg) {
            w20 += e_[mi][0][reg] * T[mi][0][reg];
            w21 += e_[mi][1][reg] * T[mi][1][reg];
        }
    w20 += __shfl_xor(w20, 16); w20 += __shfl_xor(w20, 32);
    w21 += __shfl_xor(w21, 16); w21 += __shfl_xor(w21, 32);

    // ---- P4+P5: row_sim, masked exp, LSE over words ----
    float ew = 0.f;
    if (lo < len) {
        float rs = w12p0 / fmaxf(w1v[c * WW + lo] * sqrtf(fmaxf(w20, 0.f)), 1e-30f);
        ew += __expf(LAM_LSE * rs);
    }
    if (16 + lo < len) {
        float rs = w12p1 / fmaxf(w1v[c * WW + 16 + lo] * sqrtf(fmaxf(w21, 0.f)), 1e-30f);
        ew += __expf(LAM_LSE * rs);
    }
    ew += __shfl_xor(ew, 1); ew += __shfl_xor(ew, 2);
    ew += __shfl_xor(ew, 4); ew += __shfl_xor(ew, 8);
    if (lane == 0) out[i * NC + c] = logf(ew) / LAM_LSE;
}

extern "C" void kernel_launch(void* const* d_in, const int* in_sizes, int n_in,
                              void* d_out, int out_size, void* d_ws, size_t ws_size,
                              hipStream_t stream)
{
    const float* images   = (const float*)d_in[0];
    const float* cap_emb  = (const float*)d_in[1];
    const float* W_fc     = (const float*)d_in[2];
    const float* b_fc     = (const float*)d_in[3];
    const int*   cap_lens = (const int*)d_in[4];
    float* out = (float*)d_out;

    char* ws = (char*)d_ws;
    float*          part0     = (float*)(ws);                       //  9,437,184
    float*          part1     = (float*)(ws + 9437184);             //  9,437,184
    unsigned short* images_bf = (unsigned short*)(ws + 18874368);   //  9,437,184
    unsigned short* Wt        = (unsigned short*)(ws + 28311552);   //  4,194,304
    unsigned short* img_bf    = (unsigned short*)(ws + 32505856);   //  4,718,592
    unsigned short* capn_bf   = (unsigned short*)(ws + 37224448);   //  4,194,304
    float*          w1        = (float*)(ws + 41713664);            //      8,192

    // 1. fused prep: images->bf16 | Wt | capnorm(+w1)
    prep<<<6400, 256, 0, stream>>>(images, W_fc, cap_emb, images_bf, Wt, capn_bf, w1);
    // 2. split-K=2 projection GEMM, 64x128 tiles, BK=64 swizzled
    gemm_proj64<MROWS, DD, DI, 2><<<dim3(MROWS / 64, DD / 128, 2), 256, 0, stream>>>(images_bf, Wt, part0);
    // 3. sum halves + bias, l2norm -> bf16 only
    rownorm_add<<<MROWS, 256, 0, stream>>>(part0, part1, b_fc, img_bf);
    // 4. fused S-GEMM + Gram + epilogue
    sim_fused<<<dim3(16, NI), 256, 0, stream>>>(img_bf, capn_bf, w1, cap_lens, out);
}

// Round 11
// 145.074 us; speedup vs baseline: 1.5959x; 1.0384x over previous
//
#include <hip/hip_runtime.h>

// Problem constants (fixed by setup_inputs)
constexpr int NI = 64;    // images
constexpr int NC = 64;    // captions
constexpr int RR = 36;    // regions
constexpr int WW = 32;    // max words
constexpr int DI = 2048;  // img_dim
constexpr int DD = 1024;  // d
constexpr int MROWS = NI * RR;  // 2304
constexpr int NCOLS = NC * WW;  // 2048

#define EPSV 1e-8f
#define LAM_SM 9.0f
#define LAM_LSE 6.0f
#define LEAKY_S 0.1f

typedef __bf16 bf16x8 __attribute__((ext_vector_type(8)));
typedef float f32x4 __attribute__((ext_vector_type(4)));
typedef unsigned short ushort8v __attribute__((ext_vector_type(8)));
typedef unsigned short ushort4v __attribute__((ext_vector_type(4)));

__device__ __forceinline__ unsigned short f2bf(float f) {
    unsigned int u = __builtin_bit_cast(unsigned int, f);
    unsigned int r = (u + 0x7fffu + ((u >> 16) & 1u)) >> 16;
    return (unsigned short)r;
}

#define GLOAD16(gp, lp)                                                              \
    __builtin_amdgcn_global_load_lds(                                                \
        (const __attribute__((address_space(1))) unsigned int*)(gp),                 \
        (__attribute__((address_space(3))) unsigned int*)(lp), 16, 0, 0)

// ---------------- fused prep: images->bf16 | W_fc transpose->bf16 | capnorm ----------------
__global__ __launch_bounds__(256) void prep(const float* __restrict__ images,
                                            const float* __restrict__ W,
                                            const float* __restrict__ cap,
                                            unsigned short* __restrict__ images_bf,
                                            unsigned short* __restrict__ Wt,
                                            unsigned short* __restrict__ capn_bf,
                                            float* __restrict__ w1)
{
    const int b = blockIdx.x, tid = threadIdx.x;
    if (b < 2304) {
        int i = b * 256 + tid;
        const float4* X4 = reinterpret_cast<const float4*>(images);
        float4 a = X4[i * 2], c = X4[i * 2 + 1];
        ushort8v o;
        o[0] = f2bf(a.x); o[1] = f2bf(a.y); o[2] = f2bf(a.z); o[3] = f2bf(a.w);
        o[4] = f2bf(c.x); o[5] = f2bf(c.y); o[6] = f2bf(c.z); o[7] = f2bf(c.w);
        *reinterpret_cast<ushort8v*>(&images_bf[i * 8]) = o;
    } else if (b < 4352) {
        __shared__ float t[32][33];
        int bi = b - 2304;
        int bk = (bi >> 5) * 32;
        int bn = (bi & 31) * 32;
        int x = tid & 31, y0 = tid >> 5;
        for (int yy = y0; yy < 32; yy += 8)
            t[yy][x] = W[(bk + yy) * DD + bn + x];
        __syncthreads();
        for (int yy = y0; yy < 32; yy += 8)
            Wt[(bn + yy) * DI + bk + x] = f2bf(t[x][yy]);
    } else {
        int row = b - 4352;
        float4 v = *reinterpret_cast<const float4*>(&cap[row * 1024 + tid * 4]);
        float s = v.x * v.x + v.y * v.y + v.z * v.z + v.w * v.w;
        #pragma unroll
        for (int off = 32; off; off >>= 1) s += __shfl_down(s, off);
        __shared__ float ps[4];
        if ((tid & 63) == 0) ps[tid >> 6] = s;
        __syncthreads();
        float tot = ps[0] + ps[1] + ps[2] + ps[3];
        float n = sqrtf(tot);
        float inv = 1.0f / (n + EPSV);
        v.x *= inv; v.y *= inv; v.z *= inv; v.w *= inv;
        ushort4v o;
        o[0] = f2bf(v.x); o[1] = f2bf(v.y); o[2] = f2bf(v.z); o[3] = f2bf(v.w);
        *reinterpret_cast<ushort4v*>(&capn_bf[row * 1024 + tid * 4]) = o;
        if (tid == 0) w1[row] = n * inv;
    }
}

// ---------------- projection GEMM: 64x128 tile, BK=64, XOR-swizzled LDS, split-K (R8-proven) ----------------
template <int M, int N, int K, int KS>
__global__ __launch_bounds__(256) void gemm_proj64(const unsigned short* __restrict__ A,
                                                   const unsigned short* __restrict__ Bt,
                                                   float* __restrict__ C)
{
    __shared__ __align__(16) unsigned short As[64 * 64];   // 8 KB
    __shared__ __align__(16) unsigned short Bs[128 * 64];  // 16 KB
    const int tid = threadIdx.x;
    const int w = tid >> 6, lane = tid & 63;
    const int bm = blockIdx.x * 64, bn = blockIdx.y * 128;
    const int klo = blockIdx.z * (K / KS);
    const int wr = w >> 1, wc = w & 1;
    const int hi = lane >> 4, fr = lane & 15;

    f32x4 acc[2][4] = {};

    const unsigned short* gA[2];
    const unsigned short* gB[4];
    unsigned short* lA[2];
    unsigned short* lB[4];
    #pragma unroll
    for (int n = 0; n < 2; ++n) {
        int s = tid + n * 256;
        int row = s >> 3, j = (s & 7) ^ (row & 7);
        gA[n] = &A[(size_t)(bm + row) * K + klo + j * 8];
        lA[n] = &As[s * 8];
    }
    #pragma unroll
    for (int n = 0; n < 4; ++n) {
        int s = tid + n * 256;
        int row = s >> 3, j = (s & 7) ^ (row & 7);
        gB[n] = &Bt[(size_t)(bn + row) * K + klo + j * 8];
        lB[n] = &Bs[s * 8];
    }

    for (int k0 = 0; k0 < K / KS; k0 += 64) {
        __syncthreads();
        #pragma unroll
        for (int n = 0; n < 2; ++n) GLOAD16(gA[n] + k0, lA[n]);
        #pragma unroll
        for (int n = 0; n < 4; ++n) GLOAD16(gB[n] + k0, lB[n]);
        __syncthreads();
        #pragma unroll
        for (int ks = 0; ks < 2; ++ks) {
            bf16x8 af[2], bfv[4];
            #pragma unroll
            for (int mi = 0; mi < 2; ++mi) {
                int row = wr * 32 + mi * 16 + fr;
                af[mi] = *reinterpret_cast<const bf16x8*>(
                    &As[row * 64 + ((((ks << 2) + hi) ^ (row & 7)) << 3)]);
            }
            #pragma unroll
            for (int ni = 0; ni < 4; ++ni) {
                int row = wc * 64 + ni * 16 + fr;
                bfv[ni] = *reinterpret_cast<const bf16x8*>(
                    &Bs[row * 64 + ((((ks << 2) + hi) ^ (row & 7)) << 3)]);
            }
            #pragma unroll
            for (int mi = 0; mi < 2; ++mi)
                #pragma unroll
                for (int ni = 0; ni < 4; ++ni)
                    acc[mi][ni] = __builtin_amdgcn_mfma_f32_16x16x32_bf16(af[mi], bfv[ni], acc[mi][ni], 0, 0, 0);
        }
    }

    float* Cz = C + (size_t)blockIdx.z * M * N;
    const int cr0 = hi * 4, cc = fr;
    #pragma unroll
    for (int mi = 0; mi < 2; ++mi) {
        int row0 = bm + wr * 32 + mi * 16 + cr0;
        #pragma unroll
        for (int ni = 0; ni < 4; ++ni) {
            int col = bn + wc * 64 + ni * 16 + cc;
            #pragma unroll
            for (int r = 0; r < 4; ++r)
                Cz[(size_t)(row0 + r) * N + col] = acc[mi][ni][r];
        }
    }
}

// ---------------- rownorm: v = part0 + part1 + bias; l2norm; bf16 out only ----------------
__global__ __launch_bounds__(256) void rownorm_add(const float* __restrict__ P0,
                                                   const float* __restrict__ P1,
                                                   const float* __restrict__ bias,
                                                   unsigned short* __restrict__ Xbf)
{
    const int row = blockIdx.x;
    const int t4 = threadIdx.x * 4;
    float4 a = *reinterpret_cast<const float4*>(&P0[row * 1024 + t4]);
    float4 b = *reinterpret_cast<const float4*>(&P1[row * 1024 + t4]);
    float4 c = *reinterpret_cast<const float4*>(&bias[t4]);
    float4 v = {a.x + b.x + c.x, a.y + b.y + c.y, a.z + b.z + c.z, a.w + b.w + c.w};
    float s = v.x * v.x + v.y * v.y + v.z * v.z + v.w * v.w;
    #pragma unroll
    for (int off = 32; off; off >>= 1) s += __shfl_down(s, off);
    __shared__ float ps[4];
    if ((threadIdx.x & 63) == 0) ps[threadIdx.x >> 6] = s;
    __syncthreads();
    float tot = ps[0] + ps[1] + ps[2] + ps[3];
    float inv = 1.0f / (sqrtf(tot) + EPSV);
    v.x *= inv; v.y *= inv; v.z *= inv; v.w *= inv;
    ushort4v o;
    o[0] = f2bf(v.x); o[1] = f2bf(v.y); o[2] = f2bf(v.z); o[3] = f2bf(v.w);
    *reinterpret_cast<ushort4v*>(&Xbf[row * 1024 + t4]) = o;
}

// ---------------- fused S-GEMM + Gram + epilogue: BK=64, XOR-swizzled As/Bs ----------------
// block = (cg, i): image i x captions [cg*4, cg*4+4). Wave w = caption cg*4+w.
// T2 swizzle (rule #21 both-sides, proj64-proven): LDS slot (row, j) holds
// global chunk j^(row&7); reads use chunk ((ks<<2)+hi)^(lo&7). 128B rows ->
// all 32 banks, 2-way max. Eb/Gb use 72-elem row stride (144B -> 2-way on P3
// reads; old 64-stride was 16-way). Sync structure unchanged from R10.
__global__ __launch_bounds__(256) void sim_fused(const unsigned short* __restrict__ img_bf,
                                                 const unsigned short* __restrict__ capn_bf,
                                                 const float* __restrict__ w1v,
                                                 const int* __restrict__ cap_lens,
                                                 float* __restrict__ out)
{
    __shared__ __align__(16) unsigned short As[48 * 64];      // 6 KB (swizzled chunks)
    __shared__ __align__(16) unsigned short Bs[128 * 64];     // 16 KB
    __shared__ __align__(16) unsigned short Gb[48 * 72];      // 6.75 KB (stride 72)
    __shared__ __align__(16) unsigned short Eb[4][32 * 72];   // 18 KB
    const int tid = threadIdx.x;
    const int w = tid >> 6, lane = tid & 63;
    const int i = blockIdx.y, cg = blockIdx.x;
    const int c = cg * 4 + w;
    const int hi = lane >> 4, lo = lane & 15;

    // zero Gb elems 48..63 (all 48 rows) and Eb elems 48..63 (pads 64..71 never read by MFMA)
    {
        unsigned int* gdst = (unsigned int*)Gb;
        for (int e = tid; e < 48 * 8; e += 256)
            gdst[(e >> 3) * 36 + 24 + (e & 7)] = 0;
        unsigned int* ed = (unsigned int*)Eb;
        for (int e2 = tid; e2 < 4 * 32 * 8; e2 += 256) {
            int slab = e2 >> 8, rem = e2 & 255;
            ed[slab * 1152 + (rem >> 3) * 36 + 24 + (rem & 7)] = 0;
        }
    }

    // ---- staging addresses (computed for all waves; wave 3 skips A issues) ----
    // A: 384 slots (48 rows x 8 chunks), waves 0..2 x 2 calls x 64 lanes.
    // B: 1024 slots (128 rows x 8 chunks), 4 waves x 4 calls x 64 lanes.
    const unsigned short* gAs[2];
    unsigned short* lAs[2];
    #pragma unroll
    for (int n = 0; n < 2; ++n) {
        int s = w * 128 + n * 64 + lane;          // wave-uniform base + lane (GLOAD16 convention)
        int row = s >> 3, j = (s & 7) ^ (row & 7);
        gAs[n] = &img_bf[(size_t)(i * RR + row) * DD + j * 8];
        lAs[n] = &As[s * 8];
    }
    const unsigned short* gBs[4];
    unsigned short* lBs[4];
    #pragma unroll
    for (int n = 0; n < 4; ++n) {
        int s = w * 256 + n * 64 + lane;
        int row = s >> 3, j = (s & 7) ^ (row & 7);
        gBs[n] = &capn_bf[(size_t)(cg * 128 + row) * DD + j * 8];
        lBs[n] = &Bs[s * 8];
    }

    // ---- K-loop: S GEMM (48x128) + G GEMM (48x48), BK=64, 16 iterations ----
    f32x4 acc[3][2] = {};
    f32x4 gacc0 = {0.f, 0.f, 0.f, 0.f}, gacc1 = {0.f, 0.f, 0.f, 0.f}, gacc2 = {0.f, 0.f, 0.f, 0.f};

    for (int k0 = 0; k0 < DD; k0 += 64) {
        __syncthreads();
        if (w < 3) { GLOAD16(gAs[0] + k0, lAs[0]); GLOAD16(gAs[1] + k0, lAs[1]); }
        GLOAD16(gBs[0] + k0, lBs[0]); GLOAD16(gBs[1] + k0, lBs[1]);
        GLOAD16(gBs[2] + k0, lBs[2]); GLOAD16(gBs[3] + k0, lBs[3]);
        __syncthreads();
        #pragma unroll
        for (int ks = 0; ks < 2; ++ks) {
            const int co = ((((ks << 2) + hi) ^ (lo & 7)) << 3);   // swizzled chunk offset (elems)
            bf16x8 b0  = *reinterpret_cast<const bf16x8*>(&Bs[(w * 32 + lo) * 64 + co]);
            bf16x8 b1  = *reinterpret_cast<const bf16x8*>(&Bs[(w * 32 + 16 + lo) * 64 + co]);
            bf16x8 af0 = *reinterpret_cast<const bf16x8*>(&As[(lo) * 64 + co]);
            bf16x8 af1 = *reinterpret_cast<const bf16x8*>(&As[(16 + lo) * 64 + co]);
            bf16x8 af2 = *reinterpret_cast<const bf16x8*>(&As[(32 + lo) * 64 + co]);
            acc[0][0] = __builtin_amdgcn_mfma_f32_16x16x32_bf16(af0, b0, acc[0][0], 0, 0, 0);
            acc[0][1] = __builtin_amdgcn_mfma_f32_16x16x32_bf16(af0, b1, acc[0][1], 0, 0, 0);
            acc[1][0] = __builtin_amdgcn_mfma_f32_16x16x32_bf16(af1, b0, acc[1][0], 0, 0, 0);
            acc[1][1] = __builtin_amdgcn_mfma_f32_16x16x32_bf16(af1, b1, acc[1][1], 0, 0, 0);
            acc[2][0] = __builtin_amdgcn_mfma_f32_16x16x32_bf16(af2, b0, acc[2][0], 0, 0, 0);
            acc[2][1] = __builtin_amdgcn_mfma_f32_16x16x32_bf16(af2, b1, acc[2][1], 0, 0, 0);
            // Gram: wave-uniform branch, all operands static registers (rule #20)
            if (w == 0) {
                gacc0 = __builtin_amdgcn_mfma_f32_16x16x32_bf16(af0, af0, gacc0, 0, 0, 0);
                gacc1 = __builtin_amdgcn_mfma_f32_16x16x32_bf16(af0, af1, gacc1, 0, 0, 0);
                gacc2 = __builtin_amdgcn_mfma_f32_16x16x32_bf16(af0, af2, gacc2, 0, 0, 0);
            } else if (w == 1) {
                gacc0 = __builtin_amdgcn_mfma_f32_16x16x32_bf16(af1, af0, gacc0, 0, 0, 0);
                gacc1 = __builtin_amdgcn_mfma_f32_16x16x32_bf16(af1, af1, gacc1, 0, 0, 0);
                gacc2 = __builtin_amdgcn_mfma_f32_16x16x32_bf16(af1, af2, gacc2, 0, 0, 0);
            } else if (w == 2) {
                gacc0 = __builtin_amdgcn_mfma_f32_16x16x32_bf16(af2, af0, gacc0, 0, 0, 0);
                gacc1 = __builtin_amdgcn_mfma_f32_16x16x32_bf16(af2, af1, gacc1, 0, 0, 0);
                gacc2 = __builtin_amdgcn_mfma_f32_16x16x32_bf16(af2, af2, gacc2, 0, 0, 0);
            }
        }
    }
    // acc[mi][ni][reg] = S[r = mi*16 + hi*4 + reg][wcol = ni*16 + lo]
    // gaccJ[reg]       = G[r = w*16 + hi*4 + reg][r' = J*16 + lo]

    // write G fragments to Gb (elems 0..47; 48..63 pre-zeroed)
    if (w < 3) {
        #pragma unroll
        for (int reg = 0; reg < 4; ++reg) {
            int grow = (w * 16 + hi * 4 + reg) * 72;
            Gb[grow + 0 * 16 + lo] = f2bf(gacc0[reg]);
            Gb[grow + 1 * 16 + lo] = f2bf(gacc1[reg]);
            Gb[grow + 2 * 16 + lo] = f2bf(gacc2[reg]);
        }
    }

    const int len = cap_lens[c];

    // ---- P1: leaky+mask, l2norm over words (per r) ----
    float a1[3][2][4];
    #pragma unroll
    for (int mi = 0; mi < 3; ++mi)
        #pragma unroll
        for (int reg = 0; reg < 4; ++reg) {
            int r = mi * 16 + hi * 4 + reg;
            float v0 = acc[mi][0][reg]; v0 = v0 > 0.f ? v0 : LEAKY_S * v0; v0 = (lo < len) ? v0 : 0.f;
            float v1 = acc[mi][1][reg]; v1 = v1 > 0.f ? v1 : LEAKY_S * v1; v1 = (16 + lo < len) ? v1 : 0.f;
            float ss = v0 * v0 + v1 * v1;
            ss += __shfl_xor(ss, 1); ss += __shfl_xor(ss, 2);
            ss += __shfl_xor(ss, 4); ss += __shfl_xor(ss, 8);
            float inv = 1.0f / (sqrtf(ss) + EPSV);
            bool valid = r < RR;
            a1[mi][0][reg] = valid ? v0 * inv : -1e30f;
            a1[mi][1][reg] = valid ? v1 * inv : -1e30f;
        }

    // ---- P2: col max over r; e = exp(9(a1-m)); w12 partial; Eb write ----
    float m0 = -1e30f, m1 = -1e30f;
    #pragma unroll
    for (int mi = 0; mi < 3; ++mi)
        #pragma unroll
        for (int reg = 0; reg < 4; ++reg) {
            m0 = fmaxf(m0, a1[mi][0][reg]);
            m1 = fmaxf(m1, a1[mi][1][reg]);
        }
    m0 = fmaxf(m0, __shfl_xor(m0, 16)); m0 = fmaxf(m0, __shfl_xor(m0, 32));
    m1 = fmaxf(m1, __shfl_xor(m1, 16)); m1 = fmaxf(m1, __shfl_xor(m1, 32));

    float e_[3][2][4];
    float w12p0 = 0.f, w12p1 = 0.f;
    #pragma unroll
    for (int mi = 0; mi < 3; ++mi)
        #pragma unroll
        for (int reg = 0; reg < 4; ++reg) {
            int r = mi * 16 + hi * 4 + reg;
            bool valid = r < RR;
            float e0 = valid ? __expf(LAM_SM * (a1[mi][0][reg] - m0)) : 0.f;
            float e1 = valid ? __expf(LAM_SM * (a1[mi][1][reg] - m1)) : 0.f;
            e_[mi][0][reg] = e0; e_[mi][1][reg] = e1;
            w12p0 += e0 * acc[mi][0][reg];
            w12p1 += e1 * acc[mi][1][reg];
            Eb[w][(lo) * 72 + r] = f2bf(e0);
            Eb[w][(16 + lo) * 72 + r] = f2bf(e1);
        }
    w12p0 += __shfl_xor(w12p0, 16); w12p0 += __shfl_xor(w12p0, 32);
    w12p1 += __shfl_xor(w12p1, 16); w12p1 += __shfl_xor(w12p1, 32);
    __syncthreads();   // orders Gb + Eb ds_writes before P3 ds_reads

    // ---- P3: T = G (48xK) x E^T (K x 32 words) via MFMA, K = 64 (padded) ----
    f32x4 T[3][2] = {};
    #pragma unroll
    for (int kk = 0; kk < 2; ++kk) {
        int kg2 = kk * 32 + hi * 8;
        bf16x8 eb0 = *reinterpret_cast<const bf16x8*>(&Eb[w][(lo) * 72 + kg2]);
        bf16x8 eb1 = *reinterpret_cast<const bf16x8*>(&Eb[w][(16 + lo) * 72 + kg2]);
        #pragma unroll
        for (int mi = 0; mi < 3; ++mi) {
            bf16x8 gf = *reinterpret_cast<const bf16x8*>(&Gb[(mi * 16 + lo) * 72 + kg2]);
            T[mi][0] = __builtin_amdgcn_mfma_f32_16x16x32_bf16(gf, eb0, T[mi][0], 0, 0, 0);
            T[mi][1] = __builtin_amdgcn_mfma_f32_16x16x32_bf16(gf, eb1, T[mi][1], 0, 0, 0);
        }
    }
    // w2sq = sum_r e * T   (garbage rows have e = 0)
    float w20 = 0.f, w21 = 0.f;
    #pragma unroll
    for (int mi = 0; mi < 3; ++mi)
        #pragma unroll
        for (int reg = 0; reg < 4; ++reg) {
            w20 += e_[mi][0][reg] * T[mi][0][reg];
            w21 += e_[mi][1][reg] * T[mi][1][reg];
        }
    w20 += __shfl_xor(w20, 16); w20 += __shfl_xor(w20, 32);
    w21 += __shfl_xor(w21, 16); w21 += __shfl_xor(w21, 32);

    // ---- P4+P5: row_sim, masked exp, LSE over words ----
    float ew = 0.f;
    if (lo < len) {
        float rs = w12p0 / fmaxf(w1v[c * WW + lo] * sqrtf(fmaxf(w20, 0.f)), 1e-30f);
        ew += __expf(LAM_LSE * rs);
    }
    if (16 + lo < len) {
        float rs = w12p1 / fmaxf(w1v[c * WW + 16 + lo] * sqrtf(fmaxf(w21, 0.f)), 1e-30f);
        ew += __expf(LAM_LSE * rs);
    }
    ew += __shfl_xor(ew, 1); ew += __shfl_xor(ew, 2);
    ew += __shfl_xor(ew, 4); ew += __shfl_xor(ew, 8);
    if (lane == 0) out[i * NC + c] = logf(ew) / LAM_LSE;
}

extern "C" void kernel_launch(void* const* d_in, const int* in_sizes, int n_in,
                              void* d_out, int out_size, void* d_ws, size_t ws_size,
                              hipStream_t stream)
{
    const float* images   = (const float*)d_in[0];
    const float* cap_emb  = (const float*)d_in[1];
    const float* W_fc     = (const float*)d_in[2];
    const float* b_fc     = (const float*)d_in[3];
    const int*   cap_lens = (const int*)d_in[4];
    float* out = (float*)d_out;

    char* ws = (char*)d_ws;
    float*          part0     = (float*)(ws);                       //  9,437,184
    float*          part1     = (float*)(ws + 9437184);             //  9,437,184
    unsigned short* images_bf = (unsigned short*)(ws + 18874368);   //  9,437,184
    unsigned short* Wt        = (unsigned short*)(ws + 28311552);   //  4,194,304
    unsigned short* img_bf    = (unsigned short*)(ws + 32505856);   //  4,718,592
    unsigned short* capn_bf   = (unsigned short*)(ws + 37224448);   //  4,194,304 (absorbs A-row overrun reads)
    float*          w1        = (float*)(ws + 41713664);            //      8,192

    // 1. fused prep: images->bf16 | Wt | capnorm(+w1)
    prep<<<6400, 256, 0, stream>>>(images, W_fc, cap_emb, images_bf, Wt, capn_bf, w1);
    // 2. split-K=2 projection GEMM, 64x128 tiles, BK=64 swizzled
    gemm_proj64<MROWS, DD, DI, 2><<<dim3(MROWS / 64, DD / 128, 2), 256, 0, stream>>>(images_bf, Wt, part0);
    // 3. sum halves + bias, l2norm -> bf16 only
    rownorm_add<<<MROWS, 256, 0, stream>>>(part0, part1, b_fc, img_bf);
    // 4. fused S-GEMM + Gram + epilogue (BK=64 swizzled)
    sim_fused<<<dim3(16, NI), 256, 0, stream>>>(img_bf, capn_bf, w1, cap_lens, out);
}